// Round 4
// baseline (351.061 us; speedup 1.0000x reference)
//
#include <hip/hip_runtime.h>

typedef __attribute__((ext_vector_type(8))) short short8;
typedef __attribute__((ext_vector_type(4))) float f32x4;

#define LSEQ   4096
#define NHEAD  8
#define DCH    64
#define HEIGHT 64
#define WIDTH  64

// ---------- helpers ----------
static __device__ __forceinline__ float bfu2f(unsigned short u) {
  return __uint_as_float(((unsigned int)u) << 16);
}
static __device__ __forceinline__ unsigned short f2bfu(float f) {
  unsigned int b = __float_as_uint(f);
  b += 0x7FFFu + ((b >> 16) & 1u);   // RNE
  return (unsigned short)(b >> 16);
}
static __device__ __forceinline__ float ldf(const void* p, int i, int isbf) {
  return isbf ? bfu2f(((const unsigned short*)p)[i]) : ((const float*)p)[i];
}
static __device__ __forceinline__ float softplus_inv(float sp) {
  float s = (sp > 20.f) ? sp : log1pf(expf(sp));
  return 1.f / s;
}
static __device__ __forceinline__ void unpack2(unsigned int u, float& lo, float& hi) {
  lo = __uint_as_float(u << 16);
  hi = __uint_as_float(u & 0xFFFF0000u);
}
static __device__ __forceinline__ void load8(const void* p, int gi, int isbf, float o[8]) {
  if (isbf) {
    uint4 u = *(const uint4*)((const unsigned short*)p + gi);
    unpack2(u.x, o[0], o[1]); unpack2(u.y, o[2], o[3]);
    unpack2(u.z, o[4], o[5]); unpack2(u.w, o[6], o[7]);
  } else {
    const float4* f4 = (const float4*)((const float*)p + gi);
    float4 a = f4[0], b = f4[1];
    o[0]=a.x; o[1]=a.y; o[2]=a.z; o[3]=a.w;
    o[4]=b.x; o[5]=b.y; o[6]=b.z; o[7]=b.w;
  }
}
static __device__ __forceinline__ void row_reduce2(float& a, float& b) {
  #pragma unroll
  for (int m = 1; m < 8; m <<= 1) { a += __shfl_xor(a, m, 64); b += __shfl_xor(b, m, 64); }
}
static __device__ __forceinline__ float row_reduce1(float a) {
  #pragma unroll
  for (int m = 1; m < 8; m <<= 1) a += __shfl_xor(a, m, 64);
  return a;
}

// ---------- dtype detection ----------
__global__ void detect_kernel(const unsigned int* __restrict__ q, int* __restrict__ flag) {
  int lane = threadIdx.x & 63;
  int hits = 0;
  #pragma unroll
  for (int i = 0; i < 4; ++i) {
    unsigned int lo = q[lane * 4 + i] & 0xFFFFu;
    unsigned int e  = (lo >> 7) & 0xFFu;
    if (lo == 0u || (e >= 110u && e <= 140u)) hits++;
  }
  #pragma unroll
  for (int m = 1; m < 64; m <<= 1) hits += __shfl_xor(hits, m, 64);
  if (lane == 0) *flag = (hits > 128) ? 1 : 0;
}

// ---------- kv kernel: 64-row sub-tiles, swizzled transpose, MFMA ----------
__global__ __launch_bounds__(256) void kv_kernel(
    const void* __restrict__ keys, const void* __restrict__ values,
    const void* __restrict__ scale_param,
    float* __restrict__ kv_p, float* __restrict__ ksum_g,
    const int* __restrict__ flagp, int chunks, int rows)
{
  __shared__ __align__(16) unsigned short kfT[64 * 72];
  __shared__ __align__(16) unsigned short vvT[64 * 72];
  __shared__ float red[256];

  const int isbf = *flagp;
  const int b = blockIdx.x;
  const int chunk = b % chunks;
  const int nh = b / chunks;
  const int h = nh & 7, n = nh >> 3;
  const int t = threadIdx.x, lane = t & 63, wid = t >> 6;
  const int quad = lane >> 4, m16 = lane & 15;
  const int r = lane >> 3, c = lane & 7, d0 = c * 8;
  const int swz = (c & 3) << 3;

  float inv_s[8];
  #pragma unroll
  for (int i = 0; i < 8; ++i) inv_s[i] = softplus_inv(ldf(scale_param, d0 + i, isbf));

  f32x4 acc[4];
  #pragma unroll
  for (int mt = 0; mt < 4; ++mt) acc[mt] = (f32x4){0.f, 0.f, 0.f, 0.f};
  float ksum_acc[8];
  #pragma unroll
  for (int i = 0; i < 8; ++i) ksum_acc[i] = 0.f;

  const int nsub = rows >> 6;   // 64 rows per sub
  for (int sub = 0; sub < nsub; ++sub) {
    #pragma unroll
    for (int pp = 0; pp < 2; ++pp) {
      const int s_loc = wid * 8 + r + pp * 32;     // 0..63
      const int sp = s_loc ^ swz;
      const int s = chunk * rows + sub * 64 + s_loc;
      const int gi = ((n * LSEQ + s) * NHEAD + h) * DCH + d0;

      float kraw[8];
      load8(keys, gi, isbf, kraw);
      float xv[8], yv[8], s2 = 0.f, s6 = 0.f;
      #pragma unroll
      for (int i = 0; i < 8; ++i) {
        xv[i] = (fmaxf(kraw[i], 0.f) + 1e-6f) * inv_s[i];
        s2 += xv[i] * xv[i];
      }
      #pragma unroll
      for (int i = 0; i < 8; ++i) {
        yv[i] = xv[i] * xv[i] * xv[i];
        s6 += yv[i] * yv[i];
      }
      row_reduce2(s2, s6);
      const float coef = sqrtf(s2 / s6);
      #pragma unroll
      for (int i = 0; i < 8; ++i) {
        float f = yv[i] * coef;
        ksum_acc[i] += f;
        kfT[(d0 + i) * 72 + sp] = f2bfu(f);
      }
      if (isbf) {
        uint4 u = *(const uint4*)((const unsigned short*)values + gi);
        unsigned short vs[8];
        *(uint4*)vs = u;
        #pragma unroll
        for (int i = 0; i < 8; ++i) vvT[(d0 + i) * 72 + sp] = vs[i];
      } else {
        float vraw[8];
        load8(values, gi, 0, vraw);
        #pragma unroll
        for (int i = 0; i < 8; ++i) vvT[(d0 + i) * 72 + sp] = f2bfu(vraw[i]);
      }
    }
    __syncthreads();

    const int v = wid * 16 + m16;
    const int vg = (v >> 3) & 3;
    short8 bv0 = *(const short8*)&vvT[v * 72 + ((quad ^ vg) << 3)];
    short8 bv1 = *(const short8*)&vvT[v * 72 + ((4 + (quad ^ vg)) << 3)];
    #pragma unroll
    for (int mt = 0; mt < 4; ++mt) {
      int d = mt * 16 + m16;
      int dg = (d >> 3) & 3;
      short8 a0 = *(const short8*)&kfT[d * 72 + ((quad ^ dg) << 3)];
      short8 a1 = *(const short8*)&kfT[d * 72 + ((4 + (quad ^ dg)) << 3)];
      acc[mt] = __builtin_amdgcn_mfma_f32_16x16x32_bf16(a0, bv0, acc[mt], 0, 0, 0);
      acc[mt] = __builtin_amdgcn_mfma_f32_16x16x32_bf16(a1, bv1, acc[mt], 0, 0, 0);
    }
    __syncthreads();
  }

  float* dst = kv_p + ((size_t)chunk * 64 + nh) * 4096;
  #pragma unroll
  for (int mt = 0; mt < 4; ++mt)
    #pragma unroll
    for (int rr = 0; rr < 4; ++rr) {
      int d = mt * 16 + quad * 4 + rr;
      dst[d * 64 + wid * 16 + m16] = acc[mt][rr];
    }

  #pragma unroll
  for (int i = 0; i < 8; ++i) {
    #pragma unroll
    for (int m = 8; m < 64; m <<= 1) ksum_acc[i] += __shfl_xor(ksum_acc[i], m, 64);
  }
  if (r == 0) {
    #pragma unroll
    for (int i = 0; i < 8; ++i) red[wid * 64 + d0 + i] = ksum_acc[i];
  }
  __syncthreads();
  if (t < 64) {
    float tot = red[t] + red[64 + t] + red[128 + t] + red[192 + t];
    atomicAdd(&ksum_g[nh * 64 + t], tot);
  }
}

// ---------- reduce: sum chunks, emit kv bf16 [nh][v][d] ----------
__global__ __launch_bounds__(256) void reduce_kernel(
    const float* __restrict__ kv_p, unsigned short* __restrict__ kvb, int chunks)
{
  int cidx = blockIdx.x * 256 + threadIdx.x;
  int nh = cidx >> 12;
  int dv = cidx & 4095;
  int d = dv >> 6, v = dv & 63;
  float s = 0.f;
  for (int ch = 0; ch < chunks; ++ch)
    s += kv_p[((size_t)ch * 64 + nh) * 4096 + dv];
  kvb[(nh * 64 + v) * 64 + d] = f2bfu(s);
}

// ---------- fused attention + depthwise-conv kernel ----------
// block = (n, h, 4-row y-slab); XCD-grouped y for values L2 locality.
// Phases: qf stage -> MFMA -> sync -> o to LDS (aliased over qf) -> conv from
// global -> sync -> final add + store.
__global__ __launch_bounds__(256) void fused_kernel(
    const void* __restrict__ queries, const void* __restrict__ values,
    const unsigned short* __restrict__ kvb, const float* __restrict__ ksum_g,
    const void* __restrict__ scale_param, const void* __restrict__ dwc_w,
    const void* __restrict__ dwc_b, void* __restrict__ out,
    const int* __restrict__ flagp)
{
  __shared__ __align__(16) unsigned short qfo[256 * 72];  // 36 KB: qf then o
  __shared__ float wl[25 * 64];                           // [tap][ch] fp32
  __shared__ float bl[64];

  const int isbf = *flagp;
  const int b = blockIdx.x;
  // xcd = b&7 handles y in [xcd*8, xcd*8+8)
  const int xcd = b & 7;
  const int rest = b >> 3;            // 0..127
  const int nh = rest & 63;
  const int y0 = xcd * 8 + (rest >> 6) * 4;
  const int h = nh & 7, n = nh >> 3;
  const int t = threadIdx.x, lane = t & 63, wid = t >> 6;
  const int quad = lane >> 4, m16 = lane & 15;
  const int r = lane >> 3, c = lane & 7, d0 = c * 8;

  // stage weights/bias
  for (int i = t; i < 25 * 64; i += 256) {
    int d = i / 25, tap = i - d * 25;
    wl[tap * 64 + d] = ldf(dwc_w, i, isbf);
  }
  if (t < 64) bl[t] = ldf(dwc_b, t, isbf);

  float inv_s[8];
  #pragma unroll
  for (int i = 0; i < 8; ++i) inv_s[i] = softplus_inv(ldf(scale_param, d0 + i, isbf));
  float ks[8];
  {
    float4 k0 = *(const float4*)&ksum_g[nh * 64 + d0];
    float4 k1 = *(const float4*)&ksum_g[nh * 64 + d0 + 4];
    ks[0]=k0.x; ks[1]=k0.y; ks[2]=k0.z; ks[3]=k0.w;
    ks[4]=k1.x; ks[5]=k1.y; ks[6]=k1.z; ks[7]=k1.w;
  }

  // ---- phase 1: qf staging (256 p-rows = 4 y-rows x 64 x), z folded ----
  #pragma unroll
  for (int batch = 0; batch < 8; ++batch) {
    int p = wid * 64 + batch * 8 + r;      // 0..255
    int x = p & 63, yy = y0 + (p >> 6);
    int gi = ((n * LSEQ + yy * 64 + x) * NHEAD + h) * DCH + d0;
    float qraw[8];
    load8(queries, gi, isbf, qraw);
    float xv[8], yv[8], s2 = 0.f, s6 = 0.f;
    #pragma unroll
    for (int i = 0; i < 8; ++i) {
      xv[i] = (fmaxf(qraw[i], 0.f) + 1e-6f) * inv_s[i];
      s2 += xv[i] * xv[i];
    }
    #pragma unroll
    for (int i = 0; i < 8; ++i) {
      yv[i] = xv[i] * xv[i] * xv[i];
      s6 += yv[i] * yv[i];
    }
    row_reduce2(s2, s6);
    const float coef = sqrtf(s2 / s6);
    float f[8], dot = 0.f;
    #pragma unroll
    for (int i = 0; i < 8; ++i) { f[i] = yv[i] * coef; dot += f[i] * ks[i]; }
    dot = row_reduce1(dot);
    const float z = 1.f / (dot + 1e-6f);
    uint4 pk;
    pk.x = (unsigned int)f2bfu(f[0] * z) | ((unsigned int)f2bfu(f[1] * z) << 16);
    pk.y = (unsigned int)f2bfu(f[2] * z) | ((unsigned int)f2bfu(f[3] * z) << 16);
    pk.z = (unsigned int)f2bfu(f[4] * z) | ((unsigned int)f2bfu(f[5] * z) << 16);
    pk.w = (unsigned int)f2bfu(f[6] * z) | ((unsigned int)f2bfu(f[7] * z) << 16);
    *(uint4*)&qfo[p * 72 + d0] = pk;
  }
  __syncthreads();

  // ---- phase 2: MFMA O[p][v] = qf[p][k] * kv[k][v] ----
  const int v = wid * 16 + m16;
  const unsigned short* kvrow = kvb + (nh * 64 + v) * 64;
  short8 bfr0 = *(const short8*)&kvrow[quad * 8];
  short8 bfr1 = *(const short8*)&kvrow[32 + quad * 8];
  f32x4 acc[16];
  #pragma unroll
  for (int mt = 0; mt < 16; ++mt) {
    acc[mt] = (f32x4){0.f, 0.f, 0.f, 0.f};
    short8 a0 = *(const short8*)&qfo[(mt * 16 + m16) * 72 + quad * 8];
    short8 a1 = *(const short8*)&qfo[(mt * 16 + m16) * 72 + 32 + quad * 8];
    acc[mt] = __builtin_amdgcn_mfma_f32_16x16x32_bf16(a0, bfr0, acc[mt], 0, 0, 0);
    acc[mt] = __builtin_amdgcn_mfma_f32_16x16x32_bf16(a1, bfr1, acc[mt], 0, 0, 0);
  }
  __syncthreads();   // all qf reads done

  // ---- phase 3: write o (bf16) into the qf region ----
  #pragma unroll
  for (int mt = 0; mt < 16; ++mt)
    #pragma unroll
    for (int rg = 0; rg < 4; ++rg) {
      int p = mt * 16 + quad * 4 + rg;
      qfo[p * 72 + v] = f2bfu(acc[mt][rg]);
    }

  // ---- phase 4: depthwise conv from global, register z-cache ----
  const int xx = t & 63, jb = t >> 6;
  float ca[2][4][8];
  #pragma unroll
  for (int ji = 0; ji < 2; ++ji) {
    const int jj = jb + ji * 4;
    {
      float4 b0 = *(const float4*)&bl[jj * 8];
      float4 b1 = *(const float4*)&bl[jj * 8 + 4];
      #pragma unroll
      for (int rr = 0; rr < 4; ++rr) {
        ca[ji][rr][0]=b0.x; ca[ji][rr][1]=b0.y; ca[ji][rr][2]=b0.z; ca[ji][rr][3]=b0.w;
        ca[ji][rr][4]=b1.x; ca[ji][rr][5]=b1.y; ca[ji][rr][6]=b1.z; ca[ji][rr][7]=b1.w;
      }
    }
    #pragma unroll
    for (int z = 0; z < 8; ++z) {
      int yy = y0 - 2 + z;
      if (yy < 0 || yy >= HEIGHT) continue;   // block-uniform branch
      float win[5][8];
      #pragma unroll
      for (int kx = 0; kx < 5; ++kx) {
        int xs = xx + kx - 2;
        bool ok = (unsigned)xs < (unsigned)WIDTH;
        if (isbf) {
          uint4 pv = {0u,0u,0u,0u};
          if (ok) pv = *(const uint4*)((const unsigned short*)values +
                       (((n * LSEQ + yy * 64 + xs) * NHEAD + h) * DCH + jj * 8));
          unpack2(pv.x, win[kx][0], win[kx][1]); unpack2(pv.y, win[kx][2], win[kx][3]);
          unpack2(pv.z, win[kx][4], win[kx][5]); unpack2(pv.w, win[kx][6], win[kx][7]);
        } else {
          float4 a = {0,0,0,0}, bq = {0,0,0,0};
          if (ok) {
            const float4* f4 = (const float4*)((const float*)values +
                       (((n * LSEQ + yy * 64 + xs) * NHEAD + h) * DCH + jj * 8));
            a = f4[0]; bq = f4[1];
          }
          win[kx][0]=a.x; win[kx][1]=a.y; win[kx][2]=a.z; win[kx][3]=a.w;
          win[kx][4]=bq.x; win[kx][5]=bq.y; win[kx][6]=bq.z; win[kx][7]=bq.w;
        }
      }
      #pragma unroll
      for (int ky = 0; ky < 5; ++ky) {
        const int rr = z - ky;
        if (rr < 0 || rr > 3) continue;       // compile-time (z,ky unrolled)
        #pragma unroll
        for (int kx = 0; kx < 5; ++kx) {
          float4 w0 = *(const float4*)&wl[(ky * 5 + kx) * 64 + jj * 8];
          float4 w1 = *(const float4*)&wl[(ky * 5 + kx) * 64 + jj * 8 + 4];
          ca[ji][rr][0] += w0.x * win[kx][0]; ca[ji][rr][1] += w0.y * win[kx][1];
          ca[ji][rr][2] += w0.z * win[kx][2]; ca[ji][rr][3] += w0.w * win[kx][3];
          ca[ji][rr][4] += w1.x * win[kx][4]; ca[ji][rr][5] += w1.y * win[kx][5];
          ca[ji][rr][6] += w1.z * win[kx][6]; ca[ji][rr][7] += w1.w * win[kx][7];
        }
      }
    }
  }
  __syncthreads();   // o writes visible

  // ---- phase 5: final add + store ----
  #pragma unroll
  for (int ji = 0; ji < 2; ++ji) {
    const int jj = jb + ji * 4;
    #pragma unroll
    for (int rr = 0; rr < 4; ++rr) {
      int p = rr * 64 + xx;
      uint4 ov = *(const uint4*)&qfo[p * 72 + jj * 8];
      float o0,o1,o2,o3,o4,o5,o6,o7;
      unpack2(ov.x, o0, o1); unpack2(ov.y, o2, o3);
      unpack2(ov.z, o4, o5); unpack2(ov.w, o6, o7);
      float r0 = o0 + ca[ji][rr][0], r1 = o1 + ca[ji][rr][1];
      float r2 = o2 + ca[ji][rr][2], r3 = o3 + ca[ji][rr][3];
      float r4 = o4 + ca[ji][rr][4], r5 = o5 + ca[ji][rr][5];
      float r6 = o6 + ca[ji][rr][6], r7 = o7 + ca[ji][rr][7];
      size_t oi = (((size_t)n * LSEQ + (y0 + rr) * 64 + xx) * NHEAD + h) * DCH + jj * 8;
      if (isbf) {
        uint4 res;
        res.x = (unsigned int)f2bfu(r0) | ((unsigned int)f2bfu(r1) << 16);
        res.y = (unsigned int)f2bfu(r2) | ((unsigned int)f2bfu(r3) << 16);
        res.z = (unsigned int)f2bfu(r4) | ((unsigned int)f2bfu(r5) << 16);
        res.w = (unsigned int)f2bfu(r6) | ((unsigned int)f2bfu(r7) << 16);
        *(uint4*)((unsigned short*)out + oi) = res;
      } else {
        float* op = (float*)out + oi;
        float4 q0 = {r0, r1, r2, r3};
        float4 q1 = {r4, r5, r6, r7};
        *(float4*)op = q0;
        *(float4*)(op + 4) = q1;
      }
    }
  }
}

// ---------- launch ----------
extern "C" void kernel_launch(void* const* d_in, const int* in_sizes, int n_in,
                              void* d_out, int out_size, void* d_ws, size_t ws_size,
                              hipStream_t stream) {
  int chunks = 16;
  while (chunks > 1) {
    size_t need = (size_t)chunks * 64 * 4096 * 4 + 64 * 4096 * 2 + 4096 * 4 + 64;
    if (need <= ws_size) break;
    chunks >>= 1;
  }
  const int rows = LSEQ / chunks;

  float* kv_p = (float*)d_ws;
  unsigned short* kvb = (unsigned short*)(kv_p + (size_t)chunks * 64 * 4096);
  float* ksum = (float*)(kvb + 64 * 4096);
  int* flag = (int*)(ksum + 4096);

  hipMemsetAsync(ksum, 0, 4096 * sizeof(float), stream);
  detect_kernel<<<1, 64, 0, stream>>>((const unsigned int*)d_in[0], flag);
  kv_kernel<<<64 * chunks, 256, 0, stream>>>(
      d_in[1], d_in[2], d_in[3], kv_p, ksum, flag, chunks, rows);
  reduce_kernel<<<1024, 256, 0, stream>>>(kv_p, kvb, chunks);
  fused_kernel<<<1024, 256, 0, stream>>>(
      d_in[0], d_in[2], kvb, ksum, d_in[3], d_in[4], d_in[5], d_out, flag);
}